// Round 3
// baseline (101.787 us; speedup 1.0000x reference)
//
#include <hip/hip_runtime.h>
#include <hip/hip_bf16.h>

// out[b, t] = w[t] * q0[b] + b[t]   (B x T x 1 output, fp32)
// Sequential-write layout: 1024-thread blocks, each thread owns one t4
// column (w/b in registers), block sweeps 64 consecutive rows -> each
// unrolled iteration emits one contiguous 64 KiB write burst.

typedef float f32x4 __attribute__((ext_vector_type(4)));

__device__ inline float4 fma4(float q, const float4& w, const float4& b) {
    float4 o;
    o.x = fmaf(q, w.x, b.x);
    o.y = fmaf(q, w.y, b.y);
    o.z = fmaf(q, w.z, b.z);
    o.w = fmaf(q, w.w, b.w);
    return o;
}

__device__ inline void nt_store4(float4 v, float4* p) {
    __builtin_nontemporal_store(*reinterpret_cast<f32x4*>(&v),
                                reinterpret_cast<f32x4*>(p));
}

// Specialized: T == 4096 (T4 == 1024). One float4 column per thread.
__global__ __launch_bounds__(1024)
void pn_seq1(const float* __restrict__ q0,
             const float4* __restrict__ w4,
             const float4* __restrict__ b4,
             float4* __restrict__ out4,
             int rows_per_blk) {
    const int T4 = 1024;
    const int tid = threadIdx.x;
    const float4 wv = w4[tid];
    const float4 bv = b4[tid];
    const int r0 = blockIdx.x * rows_per_blk;

    #pragma unroll 1
    for (int r = 0; r < rows_per_blk; r += 4) {
        const float4 qv = *reinterpret_cast<const float4*>(q0 + r0 + r);
        float4* p = out4 + (long long)(r0 + r) * T4 + tid;
        nt_store4(fma4(qv.x, wv, bv), p);
        nt_store4(fma4(qv.y, wv, bv), p + T4);
        nt_store4(fma4(qv.z, wv, bv), p + 2 * T4);
        nt_store4(fma4(qv.w, wv, bv), p + 3 * T4);
    }
}

// General column-stationary fallback (round-2 kernel).
__global__ __launch_bounds__(256)
void pn_colkernel(const float* __restrict__ q0,
                  const float4* __restrict__ w4,
                  const float4* __restrict__ b4,
                  float4* __restrict__ out4,
                  int T4, int rows_per_blk) {
    const int t4 = blockIdx.y * blockDim.x + threadIdx.x;
    const float4 wv = w4[t4];
    const float4 bv = b4[t4];
    const int r0 = blockIdx.x * rows_per_blk;

    #pragma unroll 1
    for (int r = 0; r < rows_per_blk; r += 4) {
        const float4 qv = *reinterpret_cast<const float4*>(q0 + r0 + r);
        const long long base = (long long)(r0 + r) * T4 + t4;
        nt_store4(fma4(qv.x, wv, bv), out4 + base);
        nt_store4(fma4(qv.y, wv, bv), out4 + base + T4);
        nt_store4(fma4(qv.z, wv, bv), out4 + base + 2LL * T4);
        nt_store4(fma4(qv.w, wv, bv), out4 + base + 3LL * T4);
    }
}

// Scalar fallback for odd shapes.
__global__ __launch_bounds__(256)
void pn_rowkernel_scalar(const float* __restrict__ q0,
                         const float* __restrict__ w,
                         const float* __restrict__ b,
                         float* __restrict__ out,
                         int T) {
    const int row = blockIdx.x;
    const float q = q0[row];
    float* __restrict__ orow = out + (long long)row * T;
    for (int j = threadIdx.x; j < T; j += blockDim.x) {
        orow[j] = fmaf(q, w[j], b[j]);
    }
}

extern "C" void kernel_launch(void* const* d_in, const int* in_sizes, int n_in,
                              void* d_out, int out_size, void* d_ws, size_t ws_size,
                              hipStream_t stream) {
    const float* q0 = (const float*)d_in[0];   // [B, 1]
    const float* w  = (const float*)d_in[1];   // [T]
    const float* b  = (const float*)d_in[2];   // [T]
    float* out = (float*)d_out;                // [B, T, 1]

    const int B = in_sizes[0];
    const int T = in_sizes[1];

    if (T == 4096 && (B % 64) == 0) {
        const int rows_per_blk = 64;           // 512 blocks = 2 per CU
        pn_seq1<<<B / rows_per_blk, 1024, 0, stream>>>(
            q0,
            reinterpret_cast<const float4*>(w),
            reinterpret_cast<const float4*>(b),
            reinterpret_cast<float4*>(out),
            rows_per_blk);
        return;
    }

    if ((T & 3) == 0) {
        const int T4 = T >> 2;
        const int rows_per_blk = 64;
        if ((T4 % 256) == 0 && (B % rows_per_blk) == 0) {
            dim3 grid(B / rows_per_blk, T4 / 256);
            pn_colkernel<<<grid, 256, 0, stream>>>(
                q0,
                reinterpret_cast<const float4*>(w),
                reinterpret_cast<const float4*>(b),
                reinterpret_cast<float4*>(out),
                T4, rows_per_blk);
            return;
        }
    }
    pn_rowkernel_scalar<<<B, 256, 0, stream>>>(q0, w, b, out, T);
}

// Round 4
// 96.441 us; speedup vs baseline: 1.0554x; 1.0554x over previous
//
#include <hip/hip_runtime.h>
#include <hip/hip_bf16.h>

// out[b, t] = w[t] * q0[b] + b[t]   (B x T x 1 output, fp32)
// Column-stationary: each block owns a 256-float4 chunk of t, w/b live in
// registers, block sweeps 64 rows. PLAIN stores (no nontemporal hint) so the
// 256 MiB L3 can absorb dirty lines past kernel end.

__device__ inline float4 fma4(float q, const float4& w, const float4& b) {
    float4 o;
    o.x = fmaf(q, w.x, b.x);
    o.y = fmaf(q, w.y, b.y);
    o.z = fmaf(q, w.z, b.z);
    o.w = fmaf(q, w.w, b.w);
    return o;
}

__global__ __launch_bounds__(256)
void pn_colkernel(const float* __restrict__ q0,
                  const float4* __restrict__ w4,
                  const float4* __restrict__ b4,
                  float4* __restrict__ out4,
                  int T4, int rows_per_blk) {
    const int t4 = blockIdx.y * blockDim.x + threadIdx.x;
    const float4 wv = w4[t4];
    const float4 bv = b4[t4];
    const int r0 = blockIdx.x * rows_per_blk;

    #pragma unroll 1
    for (int r = 0; r < rows_per_blk; r += 4) {
        const float4 qv = *reinterpret_cast<const float4*>(q0 + r0 + r);
        const long long base = (long long)(r0 + r) * T4 + t4;
        out4[base]           = fma4(qv.x, wv, bv);
        out4[base + T4]      = fma4(qv.y, wv, bv);
        out4[base + 2 * T4]  = fma4(qv.z, wv, bv);
        out4[base + 3 * T4]  = fma4(qv.w, wv, bv);
    }
}

// Scalar fallback for odd shapes.
__global__ __launch_bounds__(256)
void pn_rowkernel_scalar(const float* __restrict__ q0,
                         const float* __restrict__ w,
                         const float* __restrict__ b,
                         float* __restrict__ out,
                         int T) {
    const int row = blockIdx.x;
    const float q = q0[row];
    float* __restrict__ orow = out + (long long)row * T;
    for (int j = threadIdx.x; j < T; j += blockDim.x) {
        orow[j] = fmaf(q, w[j], b[j]);
    }
}

extern "C" void kernel_launch(void* const* d_in, const int* in_sizes, int n_in,
                              void* d_out, int out_size, void* d_ws, size_t ws_size,
                              hipStream_t stream) {
    const float* q0 = (const float*)d_in[0];   // [B, 1]
    const float* w  = (const float*)d_in[1];   // [T]
    const float* b  = (const float*)d_in[2];   // [T]
    float* out = (float*)d_out;                // [B, T, 1]

    const int B = in_sizes[0];
    const int T = in_sizes[1];

    if ((T & 3) == 0) {
        const int T4 = T >> 2;
        const int rows_per_blk = 64;
        if ((T4 % 256) == 0 && (B % rows_per_blk) == 0 && (rows_per_blk % 4) == 0) {
            dim3 grid(B / rows_per_blk, T4 / 256);   // (512, 4) at B=32768,T=4096
            pn_colkernel<<<grid, 256, 0, stream>>>(
                q0,
                reinterpret_cast<const float4*>(w),
                reinterpret_cast<const float4*>(b),
                reinterpret_cast<float4*>(out),
                T4, rows_per_blk);
            return;
        }
    }
    pn_rowkernel_scalar<<<B, 256, 0, stream>>>(q0, w, b, out, T);
}